// Round 2
// 793.582 us; speedup vs baseline: 1.1209x; 1.1209x over previous
//
#include <hip/hip_runtime.h>

#define USER_NUM 100000
#define ITEM_NUM 100000
#define NN 200000
#define DIM 64
#define EPSV 0.2f

#define NB 196          // coarse buckets of 1024 dst-nodes (ceil(200000/1024))
#define BSH 10          // bucket = dst >> 10
#define NPB 1024        // nodes per bucket
#define CH 4096         // edges per workgroup chunk in pass A
#define PER 16          // edges per thread (256*16 = 4096)
#define SRC_MASK 0x3FFFF

// ---------------------------------------------------------------------------
// K1: coarse bucket histogram (196 counters) via LDS aggregation
// ---------------------------------------------------------------------------
__global__ __launch_bounds__(256) void bhist_k(const int* __restrict__ dst,
                                               int* __restrict__ bhist, int E) {
    __shared__ int h[NB];
    int t = threadIdx.x;
    for (int i = t; i < NB; i += 256) h[i] = 0;
    __syncthreads();
    long long base = (long long)blockIdx.x * CH;
    #pragma unroll
    for (int j = 0; j < PER; ++j) {
        long long e = base + t + j * 256;
        if (e < E) atomicAdd(&h[dst[e] >> BSH], 1);
    }
    __syncthreads();
    for (int i = t; i < NB; i += 256) if (h[i]) atomicAdd(&bhist[i], h[i]);
}

// ---------------------------------------------------------------------------
// K2: exclusive scan over 196 bucket counts (single block)
// ---------------------------------------------------------------------------
__global__ __launch_bounds__(256) void bscan_k(const int* __restrict__ bhist,
                                               int* __restrict__ bucket_base,
                                               int* __restrict__ bucket_off,
                                               int* __restrict__ row_ptr, int E) {
    __shared__ int tmp[256];
    int t = threadIdx.x;
    int s = (t < NB) ? bhist[t] : 0;
    tmp[t] = s;
    __syncthreads();
    for (int off = 1; off < 256; off <<= 1) {
        int x = (t >= off) ? tmp[t - off] : 0;
        __syncthreads();
        tmp[t] += x;
        __syncthreads();
    }
    int excl = tmp[t] - s;
    if (t < NB) { bucket_base[t] = excl; bucket_off[t] = excl; }
    if (t == 0) { bucket_base[NB] = E; row_ptr[NN] = E; }
}

// ---------------------------------------------------------------------------
// K3 (pass A): LDS multi-split into 196 bucket regions, dense run writes.
// Record: x = src | (dst&1023)<<18 ; y = val bits.
// ---------------------------------------------------------------------------
__global__ __launch_bounds__(256) void apart_k(const int* __restrict__ src,
                                               const int* __restrict__ dst,
                                               const float* __restrict__ vals,
                                               int* __restrict__ bucket_off,
                                               int2* __restrict__ out, int E) {
    __shared__ int cnt[NB], start[NB], cursor[NB], gbase[NB];
    __shared__ int tmp[256];
    __shared__ int2 rec[CH];
    int t = threadIdx.x;
    long long base = (long long)blockIdx.x * CH;
    int nvalid = (int)min((long long)CH, (long long)E - base);

    int s_[PER]; int d_[PER]; float v_[PER];
    for (int i = t; i < NB; i += 256) cnt[i] = 0;
    __syncthreads();
    #pragma unroll
    for (int j = 0; j < PER; ++j) {
        int idx = t + j * 256;
        if (idx < nvalid) {
            long long e = base + idx;
            d_[j] = dst[e]; s_[j] = src[e]; v_[j] = vals[e];
            atomicAdd(&cnt[d_[j] >> BSH], 1);
        } else d_[j] = -1;
    }
    __syncthreads();
    int c = (t < NB) ? cnt[t] : 0;
    tmp[t] = c;
    __syncthreads();
    for (int off = 1; off < 256; off <<= 1) {
        int x = (t >= off) ? tmp[t - off] : 0;
        __syncthreads();
        tmp[t] += x;
        __syncthreads();
    }
    if (t < NB) {
        int excl = tmp[t] - c;
        start[t] = excl; cursor[t] = excl;
        gbase[t] = (c > 0) ? atomicAdd(&bucket_off[t], c) : 0;
    }
    __syncthreads();
    #pragma unroll
    for (int j = 0; j < PER; ++j) {
        if (d_[j] >= 0) {
            int b = d_[j] >> BSH;
            int slot = atomicAdd(&cursor[b], 1);
            rec[slot] = make_int2(s_[j] | ((d_[j] & (NPB - 1)) << 18),
                                  __float_as_int(v_[j]));
        }
    }
    __syncthreads();
    // flush: consecutive LDS slots -> contiguous global runs per bucket
    for (int slot = t; slot < nvalid; slot += 256) {
        int lo = 0, hi = NB - 1;
        while (lo < hi) {
            int mid = (lo + hi + 1) >> 1;
            if (start[mid] <= slot) lo = mid; else hi = mid - 1;
        }
        out[gbase[lo] + (slot - start[lo])] = rec[slot];
    }
}

// ---------------------------------------------------------------------------
// K4 (pass B): one WG per bucket. Per-node hist + scan in LDS -> row_ptr,
// then scatter to final CSR position (random only within ~130KB, 1 CU).
// ---------------------------------------------------------------------------
__global__ __launch_bounds__(256) void bsort_k(const int* __restrict__ bucket_base,
                                               const int2* __restrict__ in,
                                               int2* __restrict__ out,
                                               int* __restrict__ row_ptr) {
    __shared__ int noff[NPB];
    __shared__ int tmp[256];
    int b = blockIdx.x, t = threadIdx.x;
    int rbeg = bucket_base[b], rend = bucket_base[b + 1];
    for (int i = t; i < NPB; i += 256) noff[i] = 0;
    __syncthreads();
    for (int i = rbeg + t; i < rend; i += 256)
        atomicAdd(&noff[(in[i].x >> 18) & (NPB - 1)], 1);
    __syncthreads();
    // exclusive scan of 1024 counters with 256 threads (4 each)
    int l0 = noff[t * 4], l1 = noff[t * 4 + 1], l2 = noff[t * 4 + 2], l3 = noff[t * 4 + 3];
    int s = l0 + l1 + l2 + l3;
    tmp[t] = s;
    __syncthreads();
    for (int off = 1; off < 256; off <<= 1) {
        int x = (t >= off) ? tmp[t - off] : 0;
        __syncthreads();
        tmp[t] += x;
        __syncthreads();
    }
    int run = rbeg + tmp[t] - s;
    int e0 = run, e1 = run + l0, e2 = e1 + l1, e3 = e2 + l2;
    noff[t * 4] = e0; noff[t * 4 + 1] = e1; noff[t * 4 + 2] = e2; noff[t * 4 + 3] = e3;
    int node0 = b * NPB + t * 4;
    if (node0 < NN)     row_ptr[node0]     = e0;
    if (node0 + 1 < NN) row_ptr[node0 + 1] = e1;
    if (node0 + 2 < NN) row_ptr[node0 + 2] = e2;
    if (node0 + 3 < NN) row_ptr[node0 + 3] = e3;
    __syncthreads();
    for (int i = rbeg + t; i < rend; i += 256) {
        int2 r = in[i];
        int pos = atomicAdd(&noff[(r.x >> 18) & (NPB - 1)], 1);
        out[pos] = r;
    }
}

// ---------------------------------------------------------------------------
// fused segmented SpMM + noise injection + acc.
// one 64-lane wave per dst row; 4 edge-groups x 16 lanes; each lane gathers a
// float4 (4 dims) of its group's source row via global_load_dwordx4.
// ACCUMULATION IS f64: the CSR build's atomic scatter makes within-segment
// edge order vary across graph replays; sign(a) is discontinuous, and f32
// rounding jitter (~1e-5 rel) can flip it between replays -> cascading ~1.4
// divergence (round-1 failure). f64 shrinks the jitter window to ~1e-13 rel,
// making the output replay-stable. The extra cvt/fma_f64 hide under VMEM
// latency (VALUBusy was 31%).
// ---------------------------------------------------------------------------
__global__ __launch_bounds__(256) void spmm_fused_k(const int* __restrict__ row_ptr,
                                                    const int2* __restrict__ ssv,
                                                    const float* __restrict__ ego_u,
                                                    const float* __restrict__ ego_i,
                                                    float* __restrict__ ego_out,
                                                    const float* __restrict__ nz_layer,
                                                    float* __restrict__ acc,
                                                    int is_first, int is_last) {
    int node = blockIdx.x * 4 + (threadIdx.x >> 6);
    int lane = threadIdx.x & 63;
    int g    = lane >> 4;           // edge slot 0..3 within a 4-edge block
    int d4   = lane & 15;           // which float4 chunk of the 64 dims
    int beg = row_ptr[node];
    int end = row_ptr[node + 1];

    double ax = 0.0, ay = 0.0, az = 0.0, aw = 0.0;
    int base = beg;
    #pragma unroll 2
    for (; base + 4 <= end; base += 4) {
        int2 sv = ssv[base + g];
        int s = sv.x & SRC_MASK;
        double v = (double)__int_as_float(sv.y);
        const float* eb = (s < USER_NUM) ? ego_u : ego_i;
        const float4 r = *reinterpret_cast<const float4*>(eb + ((size_t)s << 6) + (d4 << 2));
        ax = fma((double)r.x, v, ax); ay = fma((double)r.y, v, ay);
        az = fma((double)r.z, v, az); aw = fma((double)r.w, v, aw);
    }
    int rem = end - base;
    if (g < rem) {
        int2 sv = ssv[base + g];
        int s = sv.x & SRC_MASK;
        double v = (double)__int_as_float(sv.y);
        const float* eb = (s < USER_NUM) ? ego_u : ego_i;
        const float4 r = *reinterpret_cast<const float4*>(eb + ((size_t)s << 6) + (d4 << 2));
        ax = fma((double)r.x, v, ax); ay = fma((double)r.y, v, ay);
        az = fma((double)r.z, v, az); aw = fma((double)r.w, v, aw);
    }
    // reduce the 4 edge groups (lane bits 4 and 5) in f64 (fixed tree order)
    ax += __shfl_xor(ax, 16, 64); ay += __shfl_xor(ay, 16, 64);
    az += __shfl_xor(az, 16, 64); aw += __shfl_xor(aw, 16, 64);
    ax += __shfl_xor(ax, 32, 64); ay += __shfl_xor(ay, 32, 64);
    az += __shfl_xor(az, 32, 64); aw += __shfl_xor(aw, 32, 64);
    float fx = (float)ax, fy = (float)ay, fz = (float)az, fw = (float)aw;

    size_t off = (size_t)node * DIM + (d4 << 2);
    const float4 nz = *reinterpret_cast<const float4*>(nz_layer + off);
    float ss = nz.x * nz.x + nz.y * nz.y + nz.z * nz.z + nz.w * nz.w;
    // reduce over the 16 dim-chunk lanes (groups hold identical copies)
    ss += __shfl_xor(ss, 1, 64);
    ss += __shfl_xor(ss, 2, 64);
    ss += __shfl_xor(ss, 4, 64);
    ss += __shfl_xor(ss, 8, 64);
    float e = EPSV / fmaxf(sqrtf(ss), 1e-12f);

    float4 val;
    val.x = fx + ((fx > 0.f) ? 1.f : ((fx < 0.f) ? -1.f : 0.f)) * nz.x * e;
    val.y = fy + ((fy > 0.f) ? 1.f : ((fy < 0.f) ? -1.f : 0.f)) * nz.y * e;
    val.z = fz + ((fz > 0.f) ? 1.f : ((fz < 0.f) ? -1.f : 0.f)) * nz.z * e;
    val.w = fw + ((fw > 0.f) ? 1.f : ((fw < 0.f) ? -1.f : 0.f)) * nz.w * e;

    if (g == 0) {
        if (!is_last) *reinterpret_cast<float4*>(ego_out + off) = val;
        float4 r4;
        if (is_first) {
            r4 = val;
        } else {
            const float4 p = *reinterpret_cast<const float4*>(acc + off);
            r4.x = p.x + val.x; r4.y = p.y + val.y;
            r4.z = p.z + val.z; r4.w = p.w + val.w;
        }
        if (is_last) {
            r4.x *= (1.0f / 3.0f); r4.y *= (1.0f / 3.0f);
            r4.z *= (1.0f / 3.0f); r4.w *= (1.0f / 3.0f);
        }
        *reinterpret_cast<float4*>(acc + off) = r4;
    }
}

extern "C" void kernel_launch(void* const* d_in, const int* in_sizes, int n_in,
                              void* d_out, int out_size, void* d_ws, size_t ws_size,
                              hipStream_t stream) {
    const float* user_emb = (const float*)d_in[0];
    const float* item_emb = (const float*)d_in[1];
    const int*   adj_src  = (const int*)d_in[2];
    const int*   adj_dst  = (const int*)d_in[3];
    const float* adj_vals = (const float*)d_in[4];
    const float* noise    = (const float*)d_in[5];
    const int E = in_sizes[2];

    const long long ND = (long long)NN * DIM;
    float* out_final = (float*)d_out;       // [NN, D] final
    float* out_cl    = out_final + ND;      // [NN, D] cl (also ego after layer 1)

    // workspace layout (~78 MB). ego_a aliases the pass-A bucketed records:
    // ssv_b is dead after bsort_k, before ego_a's first write (layer-2 spmm).
    char*  w       = (char*)d_ws;
    float* ego_a   = (float*)w;                          // ND floats (51.2 MB)
    int2*  ssv_b   = (int2*)w;                           // E records (25.6 MB), aliased
    int2*  ssv     = (int2*)(w + ND * sizeof(float));    // E records (25.6 MB)
    int*   bhist   = (int*)(ssv + E);                    // NB
    int*   bbase   = bhist + NB;                         // NB + 1
    int*   boff    = bbase + NB + 1;                     // NB
    int*   row_ptr = boff + NB;                          // NN + 1

    const int nchunk = (E + CH - 1) / CH;

    hipMemsetAsync(bhist, 0, NB * sizeof(int), stream);
    bhist_k<<<nchunk, 256, 0, stream>>>(adj_dst, bhist, E);
    bscan_k<<<1, 256, 0, stream>>>(bhist, bbase, boff, row_ptr, E);
    apart_k<<<nchunk, 256, 0, stream>>>(adj_src, adj_dst, adj_vals, boff, ssv_b, E);
    bsort_k<<<NB, 256, 0, stream>>>(bbase, ssv_b, ssv, row_ptr);

    const int spmm_grid = NN / 4;   // 200000 waves, one per dst row
    const float* item_shift = item_emb - (long long)USER_NUM * DIM;
    // layer 1: virtual concat(user,item) -> out_cl (doubles as cl), acc = val
    spmm_fused_k<<<spmm_grid, 256, 0, stream>>>(row_ptr, ssv, user_emb, item_shift,
                                                out_cl, noise, out_final, 1, 0);
    // layer 2: out_cl -> ego_a, acc += val
    spmm_fused_k<<<spmm_grid, 256, 0, stream>>>(row_ptr, ssv, out_cl, out_cl,
                                                ego_a, noise + ND, out_final, 0, 0);
    // layer 3: ego_a -> (no ego write), acc = (acc + val)/3
    spmm_fused_k<<<spmm_grid, 256, 0, stream>>>(row_ptr, ssv, ego_a, ego_a,
                                                nullptr, noise + 2 * ND, out_final, 0, 1);
}